// Round 1
// 5670.604 us; speedup vs baseline: 2.1155x; 2.1155x over previous
//
#include <hip/hip_runtime.h>
#include <math.h>

#define TT 2048
#define HH 2048
#define NH 32
#define NKV 4
#define HD 128
#define EE 64
#define II 768
#define TOPK 8
#define QKV_N 5120   // NH*HD + 2*NKV*HD
#define VOFF 4608    // NH*HD + NKV*HD
#define EPSF 1e-6f
#define RR (TT*TOPK) // 16384 expert-rows
#define BM 64
#define BN 64
#define BK 16
#define MAXT (RR/BM + EE) // 320 upper bound on ragged tiles

#define QB 64        // flash-attn q-tile
#define KBT 64       // flash-attn k-tile

// ---------------- rmsnorm over H ----------------
__global__ __launch_bounds__(256)
void rmsnorm_kernel(const float* __restrict__ x, const float* __restrict__ w,
                    float* __restrict__ y) {
  int t = blockIdx.x, tid = threadIdx.x;
  const float* row = x + (size_t)t * HH;
  float ss = 0.f;
  for (int i = tid; i < HH; i += 256) { float v = row[i]; ss += v * v; }
  for (int o = 32; o; o >>= 1) ss += __shfl_xor(ss, o, 64);
  __shared__ float red[4];
  if ((tid & 63) == 0) red[tid >> 6] = ss;
  __syncthreads();
  float tot = red[0] + red[1] + red[2] + red[3];
  float inv = rsqrtf(tot * (1.f / HH) + EPSF);
  for (int i = tid; i < HH; i += 256) y[(size_t)t * HH + i] = row[i] * inv * w[i];
}

// ---------------- fp32 tiled GEMM: C = A(MxK) @ B(KxN) [+ resid] ----------------
__global__ __launch_bounds__(256)
void sgemm_kernel(const float* __restrict__ A, const float* __restrict__ B,
                  float* __restrict__ C, const float* __restrict__ resid,
                  int M, int N, int K) {
  __shared__ float As[BK][BM + 4];
  __shared__ float Bs[BK][BN + 4];
  const int tid = threadIdx.x;
  const int bm = blockIdx.y * BM;
  const int bn = blockIdx.x * BN;
  const int tr = (tid & 15) * 4;
  const int tc = (tid >> 4) * 4;
  float acc[4][4] = {};
  for (int kb = 0; kb < K; kb += BK) {
#pragma unroll
    for (int i = 0; i < 4; ++i) {
      int e = tid + i * 256;
      As[e & 15][e >> 4] = A[(size_t)(bm + (e >> 4)) * K + kb + (e & 15)];
    }
#pragma unroll
    for (int i = 0; i < 4; ++i) {
      int e = tid + i * 256;
      Bs[e >> 6][e & 63] = B[(size_t)(kb + (e >> 6)) * N + bn + (e & 63)];
    }
    __syncthreads();
#pragma unroll
    for (int kk = 0; kk < BK; ++kk) {
      float a[4], b[4];
#pragma unroll
      for (int i = 0; i < 4; ++i) a[i] = As[kk][tr + i];
#pragma unroll
      for (int j = 0; j < 4; ++j) b[j] = Bs[kk][tc + j];
#pragma unroll
      for (int i = 0; i < 4; ++i)
#pragma unroll
        for (int j = 0; j < 4; ++j) acc[i][j] += a[i] * b[j];
    }
    __syncthreads();
  }
#pragma unroll
  for (int i = 0; i < 4; ++i)
#pragma unroll
    for (int j = 0; j < 4; ++j) {
      size_t idx = (size_t)(bm + tr + i) * N + bn + tc + j;
      C[idx] = acc[i][j] + (resid ? resid[idx] : 0.f);
    }
}

// ---------------- per-head rmsnorm + rope for q and k ----------------
__global__ __launch_bounds__(128)
void qknorm_rope_kernel(const float* __restrict__ qkv, const float* __restrict__ qw,
                        const float* __restrict__ kw, const int* __restrict__ pos,
                        float* __restrict__ qr, float* __restrict__ kr) {
  int t = blockIdx.x, hh = blockIdx.y, d = threadIdx.x;
  bool isq = hh < NH;
  const float* src = qkv + (size_t)t * QKV_N + (isq ? hh * HD : NH * HD + (hh - NH) * HD);
  float x = src[d];
  float ss = x * x;
  for (int o = 32; o; o >>= 1) ss += __shfl_xor(ss, o, 64);
  __shared__ float red[2];
  if ((d & 63) == 0) red[d >> 6] = ss;
  __syncthreads();
  float tot = red[0] + red[1];
  float inv = rsqrtf(tot * (1.f / HD) + EPSF);
  float xn = x * inv * (isq ? qw[d] : kw[d]);
  __shared__ float v[HD];
  v[d] = xn;
  __syncthreads();
  int p = pos[t];
  int i = d & 63;
  float fr = powf(10000.f, -(float)(2 * i) * (1.f / HD));
  float ang = (float)p * fr;
  float c = cosf(ang), s = sinf(ang);
  float o;
  if (d < 64) o = v[d] * c - v[d + 64] * s;
  else        o = v[d] * c + v[d - 64] * s;
  float* dst = isq ? (qr + ((size_t)t * NH + hh) * HD + d)
                   : (kr + ((size_t)t * NKV + (hh - NH)) * HD + d);
  *dst = o;
}

// ---------------- flash attention: 64q x 64k tiles, fp32, online softmax ----------------
// one block = one head x one 64-row q-tile. 256 threads.
// LDS: Qd[d][q], Kd[d][k] (transposed for b128 GEMM frags), Vs[k][d], Ps[k][q].
// Per-thread: 4x4 S-tile, 4x8 O-tile. Row-stat reduction stays inside a 16-lane
// shfl group (threads sharing rows are lanes 16g..16g+15 of one wave).
__global__ __launch_bounds__(256, 1)
void fattn_kernel(const float* __restrict__ qr, const float* __restrict__ kr,
                  const float* __restrict__ qkv, float* __restrict__ out) {
  __shared__ __align__(16) float Qd[HD][QB + 4];
  __shared__ __align__(16) float Kd[HD][KBT + 4];
  __shared__ __align__(16) float Vs[KBT][HD];
  __shared__ __align__(16) float Ps[KBT][QB + 4];
  const int h = blockIdx.x;
  const int y = blockIdx.y;
  // permute q-tiles so each CU's 4 sequential blocks sum to equal work:
  // bands {b, 15-b, 16+b, 31-b} -> constant 62 tiles total.
  const int qt = (y < 8) ? y : (y < 16 ? 23 - y : (y < 24 ? y : 55 - y));
  const int qb = qt * QB;
  const int kvh = h >> 3;          // NH/NKV = 8
  const int tid = threadIdx.x;
  const int tr = (tid >> 4) << 2;  // 4 q-rows owned
  const int tc = (tid & 15) << 2;  // 4 k-cols (S) / d-cols (PV) owned
  const float scale = 0.08838834764831845f;  // 1/sqrt(128)

  // stage Q transposed (scale folded in); coalesced loads, 2-way-free stores
  for (int it = 0; it < 32; ++it) {
    int e = it * 256 + tid;
    int q = e >> 7, d = e & 127;
    Qd[d][q] = qr[((size_t)(qb + q) * NH + h) * HD + d] * scale;
  }

  float m_i[4], l_i[4], o_acc[4][8];
#pragma unroll
  for (int i = 0; i < 4; ++i) {
    m_i[i] = -3.0e38f;
    l_i[i] = 0.f;
#pragma unroll
    for (int u = 0; u < 8; ++u) o_acc[i][u] = 0.f;
  }

  for (int kb = 0; kb <= qb; kb += KBT) {
    __syncthreads();  // prev tile's S/PV reads of Kd/Vs/Ps complete
    // stage K transposed [d][k]
    for (int it = 0; it < 32; ++it) {
      int e = it * 256 + tid;
      int k = e >> 7, d = e & 127;
      Kd[d][k] = kr[((size_t)(kb + k) * NKV + kvh) * HD + d];
    }
    // stage V [k][d], float4
    for (int it = 0; it < 8; ++it) {
      int e = it * 256 + tid;
      int k = e >> 5, d4 = (e & 31) << 2;
      *(float4*)&Vs[k][d4] =
          *(const float4*)&qkv[(size_t)(kb + k) * QKV_N + VOFF + kvh * HD + d4];
    }
    __syncthreads();

    // ---- S = (Q*scale) @ K^T : 4x4 per thread, b128 fragments ----
    float s[4][4] = {};
#pragma unroll 8
    for (int kk = 0; kk < HD; ++kk) {
      float4 a4 = *(const float4*)&Qd[kk][tr];
      float4 b4 = *(const float4*)&Kd[kk][tc];
      float a[4] = {a4.x, a4.y, a4.z, a4.w};
      float b[4] = {b4.x, b4.y, b4.z, b4.w};
#pragma unroll
      for (int i = 0; i < 4; ++i)
#pragma unroll
        for (int j = 0; j < 4; ++j) s[i][j] += a[i] * b[j];
    }

    // ---- online softmax; row group = 16 contiguous lanes of one wave ----
    const bool diag = (kb == qb);
#pragma unroll
    for (int i = 0; i < 4; ++i) {
      int r = tr + i;
      if (diag) {
#pragma unroll
        for (int j = 0; j < 4; ++j)
          if (tc + j > r) s[i][j] = -3.0e38f;
      }
      float rm = fmaxf(fmaxf(s[i][0], s[i][1]), fmaxf(s[i][2], s[i][3]));
#pragma unroll
      for (int off = 8; off; off >>= 1) rm = fmaxf(rm, __shfl_xor(rm, off, 64));
      float mn = fmaxf(m_i[i], rm);
      float al = __expf(m_i[i] - mn);
      m_i[i] = mn;
      float rs = 0.f;
#pragma unroll
      for (int j = 0; j < 4; ++j) {
        float pv = __expf(s[i][j] - mn);
        s[i][j] = pv;
        rs += pv;
      }
#pragma unroll
      for (int off = 8; off; off >>= 1) rs += __shfl_xor(rs, off, 64);
      l_i[i] = l_i[i] * al + rs;
#pragma unroll
      for (int u = 0; u < 8; ++u) o_acc[i][u] *= al;
    }
    // store P k-major for b128 PV reads
#pragma unroll
    for (int i = 0; i < 4; ++i)
#pragma unroll
      for (int j = 0; j < 4; ++j) Ps[tc + j][tr + i] = s[i][j];
    __syncthreads();

    // ---- O += P @ V : 4 rows x 8 cols per thread ----
#pragma unroll 4
    for (int kk = 0; kk < KBT; ++kk) {
      float4 p4 = *(const float4*)&Ps[kk][tr];
      float4 va = *(const float4*)&Vs[kk][tc];
      float4 vb = *(const float4*)&Vs[kk][tc + 64];
      float pr[4] = {p4.x, p4.y, p4.z, p4.w};
      float v[8] = {va.x, va.y, va.z, va.w, vb.x, vb.y, vb.z, vb.w};
#pragma unroll
      for (int i = 0; i < 4; ++i)
#pragma unroll
        for (int u = 0; u < 8; ++u) o_acc[i][u] += pr[i] * v[u];
    }
  }

  // epilogue: normalize and write two float4 per row
#pragma unroll
  for (int i = 0; i < 4; ++i) {
    float inv = 1.f / l_i[i];
    float* dst = out + ((size_t)(qb + tr + i) * NH + h) * HD;
    float4 w0 = make_float4(o_acc[i][0] * inv, o_acc[i][1] * inv,
                            o_acc[i][2] * inv, o_acc[i][3] * inv);
    float4 w1 = make_float4(o_acc[i][4] * inv, o_acc[i][5] * inv,
                            o_acc[i][6] * inv, o_acc[i][7] * inv);
    *(float4*)&dst[tc] = w0;
    *(float4*)&dst[tc + 64] = w1;
  }
}

// ---------------- gate softmax + top-8 (one wave per token) ----------------
__global__ __launch_bounds__(64)
void gate_topk_kernel(const float* __restrict__ X, const float* __restrict__ GW,
                      int* __restrict__ tidx, float* __restrict__ tw,
                      int* __restrict__ counts) {
  int t = blockIdx.x, e = threadIdx.x;
  const float* x = X + (size_t)t * HH;
  float acc = 0.f;
  for (int h = 0; h < HH; ++h) acc += x[h] * GW[(size_t)h * EE + e];
  float m = acc;
  for (int o = 32; o; o >>= 1) m = fmaxf(m, __shfl_xor(m, o, 64));
  float ex = expf(acc - m);
  float s = ex;
  for (int o = 32; o; o >>= 1) s += __shfl_xor(s, o, 64);
  float prob = ex / s;
  float v = prob;
  float myv = 0.f; int myi = -1;
  for (int r = 0; r < TOPK; ++r) {
    float mv = v; int mi = e;
    for (int o = 32; o; o >>= 1) {
      float ov = __shfl_xor(mv, o, 64);
      int oi = __shfl_xor(mi, o, 64);
      if (ov > mv || (ov == mv && oi < mi)) { mv = ov; mi = oi; }
    }
    if (e == r) { myv = mv; myi = mi; }
    if (e == mi) v = -1.f;  // probs are >= 0
  }
  float tot = myv;
  for (int o = 32; o; o >>= 1) tot += __shfl_xor(tot, o, 64);
  if (e < TOPK) {
    tidx[t * TOPK + e] = myi;
    tw[t * TOPK + e] = myv / tot;
    atomicAdd(&counts[myi], 1);
  }
}

// ---------------- build ragged schedule (1 thread) ----------------
__global__ void build_sched_kernel(const int* __restrict__ counts, int* __restrict__ offs,
                                   int* __restrict__ cur, int* __restrict__ tile_e,
                                   int* __restrict__ tile_t, int* __restrict__ ntl) {
  int off = 0, nt = 0;
  for (int e = 0; e < EE; ++e) {
    offs[e] = off;
    cur[e] = 0;
    int c = counts[e];
    off += c;
    int tiles = (c + BM - 1) / BM;
    for (int i = 0; i < tiles; ++i) { tile_e[nt] = e; tile_t[nt] = i; ++nt; }
  }
  *ntl = nt;
}

// ---------------- scatter (token,slot) into expert-sorted rows ----------------
__global__ __launch_bounds__(256)
void scatter_kernel(const int* __restrict__ tidx, const float* __restrict__ tw,
                    const int* __restrict__ offs, int* __restrict__ cur,
                    int* __restrict__ rtok, float* __restrict__ rgam) {
  int s = blockIdx.x * blockDim.x + threadIdx.x;
  if (s >= RR) return;
  int e = tidx[s];
  int p = atomicAdd(&cur[e], 1);
  int r = offs[e] + p;
  rtok[r] = s / TOPK;
  rgam[r] = tw[s];
}

// ---------------- MoE gate_up ragged GEMM + silu*up fused ----------------
__global__ __launch_bounds__(256)
void moe_gu_kernel(const float* __restrict__ X, const float* __restrict__ Wgu,
                   const int* __restrict__ rtok, const int* __restrict__ tile_e,
                   const int* __restrict__ tile_t, const int* __restrict__ ntl,
                   const int* __restrict__ offs, const int* __restrict__ counts,
                   float* __restrict__ act) {
  int bt = blockIdx.y;
  if (bt >= *ntl) return;
  int e = tile_e[bt];
  int rbase = offs[e] + tile_t[bt] * BM;
  int rlim = offs[e] + counts[e];
  int bn = blockIdx.x * BN;
  __shared__ float As[BK][BM + 4];
  __shared__ float Bg[BK][BN + 4];
  __shared__ float Bu[BK][BN + 4];
  __shared__ int toks[BM];
  int tid = threadIdx.x;
  if (tid < BM) {
    int r = rbase + tid;
    toks[tid] = (r < rlim) ? rtok[r] : -1;
  }
  __syncthreads();
  const float* W = Wgu + (size_t)e * HH * (2 * II);
  const int tr = (tid & 15) * 4, tc = (tid >> 4) * 4;
  float ag[4][4] = {}, au[4][4] = {};
  for (int kb = 0; kb < HH; kb += BK) {
#pragma unroll
    for (int i = 0; i < 4; ++i) {
      int e2 = tid + i * 256;
      int m = e2 >> 4, k = e2 & 15;
      int tk = toks[m];
      As[k][m] = (tk >= 0) ? X[(size_t)tk * HH + kb + k] : 0.f;
    }
#pragma unroll
    for (int i = 0; i < 4; ++i) {
      int e2 = tid + i * 256;
      int k = e2 >> 6, n = e2 & 63;
      size_t base = (size_t)(kb + k) * (2 * II) + bn + n;
      Bg[k][n] = W[base];
      Bu[k][n] = W[base + II];
    }
    __syncthreads();
#pragma unroll
    for (int kk = 0; kk < BK; ++kk) {
      float a[4], g[4], u[4];
#pragma unroll
      for (int i = 0; i < 4; ++i) a[i] = As[kk][tr + i];
#pragma unroll
      for (int j = 0; j < 4; ++j) { g[j] = Bg[kk][tc + j]; u[j] = Bu[kk][tc + j]; }
#pragma unroll
      for (int i = 0; i < 4; ++i)
#pragma unroll
        for (int j = 0; j < 4; ++j) { ag[i][j] += a[i] * g[j]; au[i][j] += a[i] * u[j]; }
    }
    __syncthreads();
  }
#pragma unroll
  for (int i = 0; i < 4; ++i) {
    int r = rbase + tr + i;
    if (r < rlim) {
#pragma unroll
      for (int j = 0; j < 4; ++j) {
        float gg = ag[i][j];
        float sg = gg / (1.f + expf(-gg));
        act[(size_t)r * II + bn + tc + j] = sg * au[i][j];
      }
    }
  }
}

// ---------------- MoE down ragged GEMM + weighted scatter-add ----------------
__global__ __launch_bounds__(256)
void moe_down_kernel(const float* __restrict__ Aact, const float* __restrict__ Wd,
                     const int* __restrict__ rtok, const float* __restrict__ rgam,
                     const int* __restrict__ tile_e, const int* __restrict__ tile_t,
                     const int* __restrict__ ntl, const int* __restrict__ offs,
                     const int* __restrict__ counts, float* __restrict__ out) {
  int bt = blockIdx.y;
  if (bt >= *ntl) return;
  int e = tile_e[bt];
  int rbase = offs[e] + tile_t[bt] * BM;
  int rlim = offs[e] + counts[e];
  int bn = blockIdx.x * BN;
  __shared__ float As[BK][BM + 4];
  __shared__ float Bs[BK][BN + 4];
  int tid = threadIdx.x;
  const float* W = Wd + (size_t)e * II * HH;
  const int tr = (tid & 15) * 4, tc = (tid >> 4) * 4;
  float acc[4][4] = {};
  for (int kb = 0; kb < II; kb += BK) {
#pragma unroll
    for (int i = 0; i < 4; ++i) {
      int e2 = tid + i * 256;
      int m = e2 >> 4, k = e2 & 15;
      int r = rbase + m;
      As[k][m] = (r < rlim) ? Aact[(size_t)r * II + kb + k] : 0.f;
    }
#pragma unroll
    for (int i = 0; i < 4; ++i) {
      int e2 = tid + i * 256;
      int k = e2 >> 6, n = e2 & 63;
      Bs[k][n] = W[(size_t)(kb + k) * HH + bn + n];
    }
    __syncthreads();
#pragma unroll
    for (int kk = 0; kk < BK; ++kk) {
      float a[4], b[4];
#pragma unroll
      for (int i = 0; i < 4; ++i) a[i] = As[kk][tr + i];
#pragma unroll
      for (int j = 0; j < 4; ++j) b[j] = Bs[kk][tc + j];
#pragma unroll
      for (int i = 0; i < 4; ++i)
#pragma unroll
        for (int j = 0; j < 4; ++j) acc[i][j] += a[i] * b[j];
    }
    __syncthreads();
  }
#pragma unroll
  for (int i = 0; i < 4; ++i) {
    int r = rbase + tr + i;
    if (r < rlim) {
      int tk = rtok[r];
      float gm = rgam[r];
#pragma unroll
      for (int j = 0; j < 4; ++j)
        atomicAdd(&out[(size_t)tk * HH + bn + tc + j], gm * acc[i][j]);
    }
  }
}

extern "C" void kernel_launch(void* const* d_in, const int* in_sizes, int n_in,
                              void* d_out, int out_size, void* d_ws, size_t ws_size,
                              hipStream_t stream) {
  (void)in_sizes; (void)n_in; (void)out_size; (void)ws_size;
  const float* hs  = (const float*)d_in[0];
  const int*   pos = (const int*)d_in[1];
  const float* wqkv= (const float*)d_in[2];
  const float* qnw = (const float*)d_in[3];
  const float* knw = (const float*)d_in[4];
  const float* wo  = (const float*)d_in[5];
  const float* ln1 = (const float*)d_in[6];
  const float* ln2 = (const float*)d_in[7];
  const float* gw  = (const float*)d_in[8];
  const float* wgu = (const float*)d_in[9];
  const float* wdn = (const float*)d_in[10];
  float* out = (float*)d_out;

  float* ws = (float*)d_ws;
  size_t o = 0;
  auto nextf = [&](size_t n) { float* p = ws + o; o += (n + 255) & ~(size_t)255; return p; };
  float* xn    = nextf((size_t)TT * HH);      // rmsnorm1 output, later rmsnorm2 output
  float* qkvb  = nextf((size_t)TT * QKV_N);   // qkv projection (v read from here)
  float* qr    = nextf((size_t)TT * NH * HD); // q after norm+rope
  float* kr    = nextf((size_t)TT * NKV * HD);
  float* attno = nextf((size_t)TT * NH * HD); // attention output
  float* act   = qr;                          // alias: 12.58M floats fit in qr+kr+attno (17.8M), free after wo
  float* tw    = nextf(RR);
  float* rgam  = nextf(RR);
  int* ib = (int*)(ws + o);
  int* tidx   = ib; ib += RR;
  int* counts = ib; ib += EE;
  int* offs   = ib; ib += EE;
  int* cur    = ib; ib += EE;
  int* tile_e = ib; ib += MAXT;
  int* tile_t = ib; ib += MAXT;
  int* ntl    = ib; ib += 1;
  int* rtok   = ib; ib += RR;

  hipMemsetAsync(counts, 0, EE * sizeof(int), stream);

  // 1. rmsnorm(hidden) -> xn
  rmsnorm_kernel<<<TT, 256, 0, stream>>>(hs, ln1, xn);
  // 2. qkv = xn @ wqkv
  sgemm_kernel<<<dim3(QKV_N / BN, TT / BM), 256, 0, stream>>>(xn, wqkv, qkvb, nullptr, TT, QKV_N, HH);
  // 3. per-head rmsnorm + rope
  qknorm_rope_kernel<<<dim3(TT, NH + NKV), 128, 0, stream>>>(qkvb, qnw, knw, pos, qr, kr);
  // 4. causal GQA flash attention (64x64 tiles, fp32)
  fattn_kernel<<<dim3(NH, TT / QB), 256, 0, stream>>>(qr, kr, qkvb, attno);
  // 5. out = hidden + attno @ wo   (residual 1)
  sgemm_kernel<<<dim3(HH / BN, TT / BM), 256, 0, stream>>>(attno, wo, out, hs, TT, HH, NH * HD);
  // 6. rmsnorm(out) -> xn (reused as xn2)
  rmsnorm_kernel<<<TT, 256, 0, stream>>>(out, ln2, xn);
  // 7. gate + top-8 + counts
  gate_topk_kernel<<<TT, 64, 0, stream>>>(xn, gw, tidx, tw, counts);
  // 8. offsets + ragged tile table
  build_sched_kernel<<<1, 1, 0, stream>>>(counts, offs, cur, tile_e, tile_t, ntl);
  // 9. scatter rows sorted by expert
  scatter_kernel<<<RR / 256, 256, 0, stream>>>(tidx, tw, offs, cur, rtok, rgam);
  // 10. act = silu(x@Wg) * (x@Wu), ragged per expert
  moe_gu_kernel<<<dim3(II / BN, MAXT), 256, 0, stream>>>(xn, wgu, rtok, tile_e, tile_t, ntl, offs, counts, act);
  // 11. out += gamma * (act @ Wd), scatter-add  (residual 2 already in out)
  moe_down_kernel<<<dim3(HH / BN, MAXT), 256, 0, stream>>>(act, wdn, rtok, rgam, tile_e, tile_t, ntl, offs, counts, out);
}